// Round 8
// baseline (534.784 us; speedup 1.0000x reference)
//
#include <hip/hip_runtime.h>
#include <stdint.h>

typedef unsigned short u16;
typedef __attribute__((ext_vector_type(8))) short bf16x8;
typedef __attribute__((ext_vector_type(4))) float f32x4;

__device__ __forceinline__ u16 f2bf(float f) {
    union { float f; uint32_t u; } v; v.f = f;
    uint32_t r = (v.u + 0x7FFFu + ((v.u >> 16) & 1u)) >> 16;
    return (u16)r;
}

// async global->LDS, 16B per lane; lds base must be wave-uniform
__device__ __forceinline__ void g2l16(const u16* g, u16* l) {
    __builtin_amdgcn_global_load_lds(
        (const __attribute__((address_space(1))) uint32_t*)g,
        (__attribute__((address_space(3))) uint32_t*)l, 16, 0, 0);
}

// tanh-based GELU (abs err ~3e-4 vs exact erf; threshold is 0.123)
__device__ __forceinline__ float gelu_f(float x) {
    float x2 = x * x;
    float u = x * (0.7978845608028654f + 0.035677408136300125f * x2);
    float t = exp2f(-2.8853900817779268f * fabsf(u));   // e^{-2|u|}
    float th = (1.0f - t) / (1.0f + t);
    th = (u < 0.0f) ? -th : th;
    return 0.5f * x * (1.0f + th);
}

// ---------------- fp32 -> bf16 convert (weights) ----------------
__global__ __launch_bounds__(256) void cvt_kernel(const float* __restrict__ in,
                                                  u16* __restrict__ out, int n4) {
    int i = blockIdx.x * 256 + threadIdx.x;
    if (i < n4) {
        float4 v = ((const float4*)in)[i];
        uint2 o;
        o.x = (uint32_t)f2bf(v.x) | ((uint32_t)f2bf(v.y) << 16);
        o.y = (uint32_t)f2bf(v.z) | ((uint32_t)f2bf(v.w) << 16);
        ((uint2*)out)[i] = o;
    }
}

// ---------------- LayerNorm (fp32 in, bf16 out), D=1024 ----------------
__global__ __launch_bounds__(256) void ln_kernel(const float* __restrict__ x,
                                                 const float* __restrict__ g,
                                                 const float* __restrict__ beta,
                                                 u16* __restrict__ out) {
    int row = blockIdx.x;
    int tid = threadIdx.x;
    const float4 v = ((const float4*)(x + (size_t)row * 1024))[tid];
    float s  = v.x + v.y + v.z + v.w;
    float sq = v.x*v.x + v.y*v.y + v.z*v.z + v.w*v.w;
    #pragma unroll
    for (int off = 32; off; off >>= 1) {
        s  += __shfl_xor(s,  off, 64);
        sq += __shfl_xor(sq, off, 64);
    }
    __shared__ float rs[4], rq[4];
    int w = tid >> 6;
    if ((tid & 63) == 0) { rs[w] = s; rq[w] = sq; }
    __syncthreads();
    s  = rs[0] + rs[1] + rs[2] + rs[3];
    sq = rq[0] + rq[1] + rq[2] + rq[3];
    float mu   = s * (1.0f / 1024.0f);
    float var  = sq * (1.0f / 1024.0f) - mu * mu;
    float rstd = rsqrtf(var + 1e-6f);
    float4 gv = ((const float4*)g)[tid];
    float4 bv = ((const float4*)beta)[tid];
    uint2 o;
    o.x = (uint32_t)f2bf((v.x - mu) * rstd * gv.x + bv.x) |
          ((uint32_t)f2bf((v.y - mu) * rstd * gv.y + bv.y) << 16);
    o.y = (uint32_t)f2bf((v.z - mu) * rstd * gv.z + bv.z) |
          ((uint32_t)f2bf((v.w - mu) * rstd * gv.w + bv.w) << 16);
    ((uint2*)(out + (size_t)row * 1024))[tid] = o;
}

// ============ 8-phase 256x256 GEMM (m201-schedule port) ============
// BK=64, 8 waves (2Mx4N), per-wave 128x64 out (acc[8][4]); dbuf by tile parity.
// Per phase: {ds_read frags; stage freed quarter(s); s_barrier; lgkmcnt(0);
// setprio(1); 16 MFMA; setprio(0); [vmcnt(4) at ph4/ph8]; s_barrier}.
// Quadrant order per tile: (mh0,nh0)(mh0,nh1)(mh1,nh0)(mh1,nh1); A-frags reused
// across the nh pair; B re-read (12-read phases at nh==0, 4-read otherwise).
// T2 swizzle: linear LDS dest, src col ^= (row&7)<<3, same XOR on ds_read.
template<int ACT, int RES, int OUTMODE>
__global__ __launch_bounds__(512, 2) void gemm8_kernel(
    const u16* __restrict__ A, const u16* __restrict__ W,
    const float* __restrict__ bias, const float* __restrict__ res,
    void* __restrict__ Cout, u16* __restrict__ vtb, int M, int N, int K)
{
    __shared__ u16 sA[2][256 * 64];
    __shared__ u16 sB[2][256 * 64];
    __shared__ u16 sDump[4096];   // dummy-stage target (tail iterations)

    int tid = threadIdx.x;
    int lane = tid & 63, wid = tid >> 6;
    int wm = wid >> 2, wn = wid & 3;
    int q = lane & 15, g = lane >> 4;

    int MT = M >> 8;
    int nwg = gridDim.x, bid = blockIdx.x;
    int chunk = nwg >> 3;
    int wg = (bid & 7) * chunk + (bid >> 3);   // bijective XCD swizzle (nwg%8==0)
    int mt = wg % MT, nt = wg / MT;
    int m0 = mt << 8, n0 = nt << 8;
    int NT = K >> 6, NU = NT >> 1;

    int srow = lane >> 3;          // staging row-within-8
    int scol = (lane & 7) * 8;
    const u16* Ab = A + (size_t)m0 * K;
    const u16* Wb = W + (size_t)n0 * K;

    auto stA = [&](int par, int tile, int rs, bool ok) {
        int c = scol ^ (srow << 3);                 // rs%8==0 -> row&7 == srow
        g2l16(ok ? (Ab + (size_t)(rs + srow) * K + (tile << 6) + c) : (Ab + c),
              ok ? (&sA[par][rs << 6]) : sDump);
    };
    auto stB = [&](int par, int tile, int rs, bool ok) {
        int c = scol ^ (srow << 3);
        g2l16(ok ? (Wb + (size_t)(rs + srow) * K + (tile << 6) + c) : (Wb + c),
              ok ? (&sB[par][rs << 6]) : sDump);
    };
    // A quarter qq: rows {qq*64..+63} U {128+qq*64..+63}  (read by RD_A(mh=qq))
    auto stAQ = [&](int par, int tile, int qq, bool ok) {
        stA(par, tile, qq * 64 + wid * 8, ok);
        stA(par, tile, 128 + qq * 64 + wid * 8, ok);
    };
    // B half nh: rows ≡ nh*32..+31 (mod 64)
    auto stBN = [&](int par, int tile, int nh, bool ok) {
        int rs = (wid >> 2) * 64 + (wid & 3) * 8 + nh * 32;
        stB(par, tile, rs, ok);
        stB(par, tile, rs + 128, ok);
    };

    f32x4 acc[8][4] = {};
    bf16x8 af[2][4], bv[2][2];

#define RD_A(par, mh) { _Pragma("unroll") for (int i = 0; i < 4; i++) { \
    int rowL = wm * 128 + (mh) * 64 + i * 16 + q; \
    _Pragma("unroll") for (int ks = 0; ks < 2; ks++) { \
        int colE = (ks * 32 + g * 8) ^ ((rowL & 7) << 3); \
        af[ks][i] = *(const bf16x8*)(&sA[par][rowL * 64 + colE]); } } }
#define RD_B(par, nh) { _Pragma("unroll") for (int j = 0; j < 2; j++) { \
    int rowL = wn * 64 + (nh) * 32 + j * 16 + q; \
    _Pragma("unroll") for (int ks = 0; ks < 2; ks++) { \
        int colE = (ks * 32 + g * 8) ^ ((rowL & 7) << 3); \
        bv[ks][j] = *(const bf16x8*)(&sB[par][rowL * 64 + colE]); } } }
#define MFMA16(mh, nh) { \
    __builtin_amdgcn_s_barrier(); \
    asm volatile("s_waitcnt lgkmcnt(0)" ::: "memory"); \
    __builtin_amdgcn_sched_barrier(0); \
    __builtin_amdgcn_s_setprio(1); \
    _Pragma("unroll") for (int ks = 0; ks < 2; ks++) \
    _Pragma("unroll") for (int i = 0; i < 4; i++) \
    _Pragma("unroll") for (int j = 0; j < 2; j++) \
        acc[(mh)*4+i][(nh)*2+j] = __builtin_amdgcn_mfma_f32_16x16x32_bf16( \
            af[ks][i], bv[ks][j], acc[(mh)*4+i][(nh)*2+j], 0, 0, 0); \
    __builtin_amdgcn_s_setprio(0); }
#define VM4 asm volatile("s_waitcnt vmcnt(4)" ::: "memory")
#define BAR __builtin_amdgcn_s_barrier()

    // prologue: tile0 full, tile1 {A-q0, B-nh0}; leave tile1's 4 in flight
    stAQ(0, 0, 0, true); stBN(0, 0, 0, true);
    stAQ(0, 0, 1, true); stBN(0, 0, 1, true);
    stAQ(1, 1, 0, true); stBN(1, 1, 0, true);
    VM4; BAR;

    for (int u = 0; u < NU; u++) {
        int t = 2 * u;
        bool ok2 = (t + 2 < NT), ok3 = (t + 3 < NT);
        // ---- tile t (parity 0) ----
        RD_A(0, 0); RD_B(0, 0);
        stAQ(1, t + 1, 1, true); stBN(1, t + 1, 1, true);   // t+1 tail halves
        MFMA16(0, 0); BAR;                                   // ph1
        RD_B(0, 1);
        MFMA16(0, 1); BAR;                                   // ph2
        RD_A(0, 1); RD_B(0, 0);
        stAQ(0, t + 2, 0, ok2);                              // A-q0(t+2): freed ph1
        MFMA16(1, 0); BAR;                                   // ph3
        RD_B(0, 1);
        stBN(0, t + 2, 0, ok2);                              // B-nh0(t+2): freed ph3
        MFMA16(1, 1); VM4; BAR;                              // ph4
        // ---- tile t+1 (parity 1) ----
        RD_A(1, 0); RD_B(1, 0);
        stAQ(0, t + 2, 1, ok2); stBN(0, t + 2, 1, ok2);      // freed ph3/ph4
        MFMA16(0, 0); BAR;                                   // ph5
        RD_B(1, 1);
        MFMA16(0, 1); BAR;                                   // ph6
        RD_A(1, 1); RD_B(1, 0);
        stAQ(1, t + 3, 0, ok3);                              // freed ph5
        MFMA16(1, 0); BAR;                                   // ph7
        RD_B(1, 1);
        stBN(1, t + 3, 0, ok3);                              // freed ph7
        MFMA16(1, 1); VM4; BAR;                              // ph8
    }
    asm volatile("s_waitcnt vmcnt(0)" ::: "memory");
#undef RD_A
#undef RD_B
#undef MFMA16
#undef VM4
#undef BAR

    #pragma unroll
    for (int i = 0; i < 8; i++) {
        #pragma unroll
        for (int j = 0; j < 4; j++) {
            int col = n0 + wn * 64 + j * 16 + q;
            float bz = bias[col];
            int row0 = m0 + wm * 128 + i * 16 + g * 4;
            float vv[4];
            #pragma unroll
            for (int r = 0; r < 4; r++) {
                float v = acc[i][j][r] + bz;
                if (ACT == 1) v = gelu_f(v);
                if (RES) v += res[(size_t)(row0 + r) * N + col];
                vv[r] = v;
            }
            if (OUTMODE == 0) {
                #pragma unroll
                for (int r = 0; r < 4; r++) ((float*)Cout)[(size_t)(row0 + r) * N + col] = vv[r];
            } else if (OUTMODE == 1) {
                #pragma unroll
                for (int r = 0; r < 4; r++) ((u16*)Cout)[(size_t)(row0 + r) * N + col] = f2bf(vv[r]);
            } else {
                if (col < 2048) {   // Q,K -> [row][2048]
                    #pragma unroll
                    for (int r = 0; r < 4; r++) ((u16*)Cout)[(size_t)(row0 + r) * 2048 + col] = f2bf(vv[r]);
                } else {            // V -> transposed vtb[B][H][64][1024]
                    int hd = col & 63, hh = (col >> 6) - 32;
                    int b_ = row0 >> 10, s_ = row0 & 1023;
                    ushort4 pk = { f2bf(vv[0]), f2bf(vv[1]), f2bf(vv[2]), f2bf(vv[3]) };
                    *(ushort4*)(vtb + (((size_t)(b_ * 16 + hh) * 64 + hd) << 10) + s_) = pk;
                }
            }
        }
    }
}

// ---------------- 2-phase 128x256 GEMM (kept for N=1024 shapes) ----------------
template<int ACT, int RES, int OUTMODE>
__global__ __launch_bounds__(512) void gemm2_kernel(
    const u16* __restrict__ A, const u16* __restrict__ W,
    const float* __restrict__ bias, const float* __restrict__ res,
    void* __restrict__ Cout, u16* __restrict__ vtb, int M, int N, int K)
{
    const int BM = 128, BN = 256, BK = 64;
    __shared__ u16 sA[2 * BM * BK];
    __shared__ u16 sB[2 * BN * BK];

    int tid = threadIdx.x;
    int lane = tid & 63, wid = tid >> 6;
    int wm = wid >> 2, wn = wid & 3;
    int q = lane & 15, g = lane >> 4;

    int MT = M >> 7;
    int nwg = gridDim.x;
    int chunk = nwg >> 3;
    int bid = blockIdx.x;
    int wg = (bid & 7) * chunk + (bid >> 3);
    int mt = wg % MT, nt = wg / MT;
    int m0 = mt << 7, n0 = nt << 8;
    const int NT = K >> 6;

    const u16* srcA[2]; const u16* srcB[4];
    u16* dstA[2]; u16* dstB[4];
    #pragma unroll
    for (int l = 0; l < 2; l++) {
        int idx = l * 512 + tid, row = idx >> 3;
        int col = ((idx & 7) * 8) ^ ((row & 7) << 3);
        srcA[l] = A + (size_t)(m0 + row) * K + col;
        dstA[l] = sA + (l * 512 + wid * 64) * 8;
    }
    #pragma unroll
    for (int l = 0; l < 4; l++) {
        int idx = l * 512 + tid, row = idx >> 3;
        int col = ((idx & 7) * 8) ^ ((row & 7) << 3);
        srcB[l] = W + (size_t)(n0 + row) * K + col;
        dstB[l] = sB + (l * 512 + wid * 64) * 8;
    }

    #define STAGE(bf, t) { int ko = (t) * 64; int boA = (bf) * (BM * BK); int boB = (bf) * (BN * BK); \
        g2l16(srcA[0] + ko, dstA[0] + boA); g2l16(srcA[1] + ko, dstA[1] + boA); \
        g2l16(srcB[0] + ko, dstB[0] + boB); g2l16(srcB[1] + ko, dstB[1] + boB); \
        g2l16(srcB[2] + ko, dstB[2] + boB); g2l16(srcB[3] + ko, dstB[3] + boB); }

    f32x4 acc[4][4] = {};

    STAGE(0, 0);
    STAGE(1, 1);
    asm volatile("s_waitcnt vmcnt(6)\n" ::: "memory");
    __builtin_amdgcn_s_barrier();

    int buf = 0;
    for (int t = 0; t < NT; t++) {
        const u16* bA = sA + buf * (BM * BK);
        const u16* bB = sB + buf * (BN * BK);
        bf16x8 af[2][4], bfr[2][4];
        #pragma unroll
        for (int ks = 0; ks < 2; ks++) {
            #pragma unroll
            for (int i = 0; i < 4; i++) {
                int rowL = wm * 64 + i * 16 + q;
                int colE = (ks * 32 + g * 8) ^ ((rowL & 7) << 3);
                af[ks][i] = *(const bf16x8*)(bA + rowL * 64 + colE);
            }
            #pragma unroll
            for (int j = 0; j < 4; j++) {
                int rowL = wn * 64 + j * 16 + q;
                int colE = (ks * 32 + g * 8) ^ ((rowL & 7) << 3);
                bfr[ks][j] = *(const bf16x8*)(bB + rowL * 64 + colE);
            }
        }
        asm volatile("s_waitcnt lgkmcnt(0)\n" ::: "memory");
        __builtin_amdgcn_s_barrier();
        bool pre = (t + 2 < NT);
        if (pre) STAGE(buf, t + 2);
        #pragma unroll
        for (int ks = 0; ks < 2; ks++)
            #pragma unroll
            for (int i = 0; i < 4; i++)
                #pragma unroll
                for (int j = 0; j < 4; j++)
                    acc[i][j] = __builtin_amdgcn_mfma_f32_16x16x32_bf16(af[ks][i], bfr[ks][j], acc[i][j], 0, 0, 0);
        if (pre) { asm volatile("s_waitcnt vmcnt(6)\n" ::: "memory"); }
        else     { asm volatile("s_waitcnt vmcnt(0)\n" ::: "memory"); }
        __builtin_amdgcn_s_barrier();
        buf ^= 1;
    }
    #undef STAGE

    #pragma unroll
    for (int i = 0; i < 4; i++) {
        #pragma unroll
        for (int j = 0; j < 4; j++) {
            int col = n0 + wn * 64 + j * 16 + q;
            float bz = bias[col];
            int row0 = m0 + wm * 64 + i * 16 + g * 4;
            float vv[4];
            #pragma unroll
            for (int r = 0; r < 4; r++) {
                float v = acc[i][j][r] + bz;
                if (ACT == 1) v = gelu_f(v);
                if (RES) v += res[(size_t)(row0 + r) * N + col];
                vv[r] = v;
            }
            if (OUTMODE == 0) {
                #pragma unroll
                for (int r = 0; r < 4; r++) ((float*)Cout)[(size_t)(row0 + r) * N + col] = vv[r];
            } else {
                #pragma unroll
                for (int r = 0; r < 4; r++) ((u16*)Cout)[(size_t)(row0 + r) * N + col] = f2bf(vv[r]);
            }
        }
    }
}

// ---------------- Flash attention ----------------
// qk bf16 [B,S,2,H,64] (stride 2048), vt bf16 [B,H,64,S] -> ctx bf16 [B,S,D]
// XCD-chunked block order: all (h,qt) of one b on one XCD -> K/V L2-resident.
__global__ __launch_bounds__(256) void attn_kernel(const u16* __restrict__ qk,
                                                   const u16* __restrict__ vt,
                                                   u16* __restrict__ ctx) {
    int bid = blockIdx.x;
    int idx = (bid & 7) * 256 + (bid >> 3);   // bijective; XCD gets contiguous (b,h,qt)
    int qt = idx & 15;
    int h  = (idx >> 4) & 15;
    int b  = idx >> 8;
    int tid = threadIdx.x, lane = tid & 63, w = tid >> 6;
    int q = lane & 15, g = lane >> 4;

    __shared__ u16 sK[2][64 * 72];
    __shared__ u16 sV[2][64 * 72];

    const size_t tokBase = (size_t)b * 1024 * 2048 + (size_t)h * 64;
    const u16* vbase = vt + (size_t)(b * 16 + h) * 64 * 1024;
    const float SC = 0.125f * 1.44269504088896f;  // HD^-0.5 * log2(e)

    const u16* qrow = qk + tokBase + (size_t)(qt * 64 + w * 16 + q) * 2048;
    bf16x8 qf0 = *(const bf16x8*)(qrow + g * 8);
    bf16x8 qf1 = *(const bf16x8*)(qrow + 32 + g * 8);

    int r0 = tid >> 3, c0 = (tid & 7) * 8;
    int kp0 = 8 * ((r0 >> 2) & 3) + 4 * ((r0 >> 4) & 1) + (r0 & 3);  // kappa(r0)
    int kp1 = 32 + kp0;

    {   // prologue: stage tile 0
        uint4 k0 = *(const uint4*)(qk + tokBase + (size_t)kp0 * 2048 + 1024 + c0);
        uint4 k1 = *(const uint4*)(qk + tokBase + (size_t)kp1 * 2048 + 1024 + c0);
        uint4 v0 = *(const uint4*)(vbase + (size_t)r0 * 1024 + c0);
        uint4 v1 = *(const uint4*)(vbase + (size_t)(32 + r0) * 1024 + c0);
        *(uint4*)(&sK[0][r0 * 72 + c0]) = k0;
        *(uint4*)(&sK[0][(32 + r0) * 72 + c0]) = k1;
        *(uint4*)(&sV[0][r0 * 72 + c0]) = v0;
        *(uint4*)(&sV[0][(32 + r0) * 72 + c0]) = v1;
    }
    __syncthreads();

    float m_run = -1e30f, l_run = 0.0f;
    f32x4 o[4];
    #pragma unroll
    for (int n = 0; n < 4; n++) o[n] = (f32x4){0.f, 0.f, 0.f, 0.f};

    for (int kt = 0; kt < 16; kt++) {
        int cur = kt & 1;
        uint4 kn0 = {}, kn1 = {}, vn0 = {}, vn1 = {};
        if (kt < 15) {
            size_t kb = tokBase + (size_t)((kt + 1) * 64) * 2048 + 1024 + c0;
            kn0 = *(const uint4*)(qk + kb + (size_t)kp0 * 2048);
            kn1 = *(const uint4*)(qk + kb + (size_t)kp1 * 2048);
            vn0 = *(const uint4*)(vbase + (size_t)r0 * 1024 + (kt + 1) * 64 + c0);
            vn1 = *(const uint4*)(vbase + (size_t)(32 + r0) * 1024 + (kt + 1) * 64 + c0);
        }

        // QK^T (swapped operands): 4 key-subtiles x 2 dim-halves
        f32x4 s[4];
        __builtin_amdgcn_s_setprio(1);
        #pragma unroll
        for (int c = 0; c < 4; c++) {
            s[c] = (f32x4){0.f, 0.f, 0.f, 0.f};
            bf16x8 a0 = *(const bf16x8*)(&sK[cur][(c * 16 + q) * 72 + g * 8]);
            bf16x8 a1 = *(const bf16x8*)(&sK[cur][(c * 16 + q) * 72 + 32 + g * 8]);
            s[c] = __builtin_amdgcn_mfma_f32_16x16x32_bf16(a0, qf0, s[c], 0, 0, 0);
            s[c] = __builtin_amdgcn_mfma_f32_16x16x32_bf16(a1, qf1, s[c], 0, 0, 0);
        }
        __builtin_amdgcn_s_setprio(0);
        float ps[16];
        #pragma unroll
        for (int c = 0; c < 4; c++)
            #pragma unroll
            for (int r = 0; r < 4; r++) ps[c * 4 + r] = s[c][r] * SC;

        float tm = ps[0];
        #pragma unroll
        for (int i = 1; i < 16; i++) tm = fmaxf(tm, ps[i]);
        tm = fmaxf(tm, __shfl_xor(tm, 16, 64));
        tm = fmaxf(tm, __shfl_xor(tm, 32, 64));

        if (!__all(tm - m_run <= 8.0f)) {   // defer-max (T13)
            float nm = fmaxf(m_run, tm);
            float f = exp2f(m_run - nm);
            float fr[4];
            #pragma unroll
            for (int r = 0; r < 4; r++) fr[r] = __shfl(f, g * 4 + r, 64);
            #pragma unroll
            for (int n = 0; n < 4; n++)
                #pragma unroll
                for (int r = 0; r < 4; r++) o[n][r] *= fr[r];
            l_run *= f;
            m_run = nm;
        }

        float ts = 0.0f;
        #pragma unroll
        for (int i = 0; i < 16; i++) { ps[i] = exp2f(ps[i] - m_run); ts += ps[i]; }
        ts += __shfl_xor(ts, 16, 64);
        ts += __shfl_xor(ts, 32, 64);
        l_run += ts;

        bf16x8 pf0, pf1;
        #pragma unroll
        for (int j = 0; j < 4; j++) {
            pf0[j]     = (short)f2bf(ps[j]);
            pf0[4 + j] = (short)f2bf(ps[4 + j]);
            pf1[j]     = (short)f2bf(ps[8 + j]);
            pf1[4 + j] = (short)f2bf(ps[12 + j]);
        }

        if (kt < 15) {
            *(uint4*)(&sK[cur ^ 1][r0 * 72 + c0]) = kn0;
            *(uint4*)(&sK[cur ^ 1][(32 + r0) * 72 + c0]) = kn1;
            *(uint4*)(&sV[cur ^ 1][r0 * 72 + c0]) = vn0;
            *(uint4*)(&sV[cur ^ 1][(32 + r0) * 72 + c0]) = vn1;
        }

        __builtin_amdgcn_s_setprio(1);
        #pragma unroll
        for (int n = 0; n < 4; n++) {
            bf16x8 v0 = *(const bf16x8*)(&sV[cur][(n * 16 + q) * 72 + g * 8]);
            o[n] = __builtin_amdgcn_mfma_f32_16x16x32_bf16(pf0, v0, o[n], 0, 0, 0);
        }
        #pragma unroll
        for (int n = 0; n < 4; n++) {
            bf16x8 v1 = *(const bf16x8*)(&sV[cur][(n * 16 + q) * 72 + 32 + g * 8]);
            o[n] = __builtin_amdgcn_mfma_f32_16x16x32_bf16(pf1, v1, o[n], 0, 0, 0);
        }
        __builtin_amdgcn_s_setprio(0);
        __syncthreads();
    }

    float inv = 1.0f / l_run;
    float ir[4];
    #pragma unroll
    for (int r = 0; r < 4; r++) ir[r] = __shfl(inv, g * 4 + r, 64);
    size_t outBase = ((size_t)b * 1024 + qt * 64 + w * 16) * 1024 + (size_t)h * 64;
    #pragma unroll
    for (int n = 0; n < 4; n++)
        #pragma unroll
        for (int r = 0; r < 4; r++)
            ctx[outBase + (size_t)(g * 4 + r) * 1024 + n * 16 + q] = f2bf(o[n][r] * ir[r]);
}

extern "C" void kernel_launch(void* const* d_in, const int* in_sizes, int n_in,
                              void* d_out, int out_size, void* d_ws, size_t ws_size,
                              hipStream_t stream) {
    const float* x      = (const float*)d_in[0];
    const float* qkv_w  = (const float*)d_in[1];
    const float* qkv_b  = (const float*)d_in[2];
    const float* proj_w = (const float*)d_in[3];
    const float* proj_b = (const float*)d_in[4];
    const float* fc1_w  = (const float*)d_in[5];
    const float* fc1_b  = (const float*)d_in[6];
    const float* fc2_w  = (const float*)d_in[7];
    const float* fc2_b  = (const float*)d_in[8];
    const float* ln1_g  = (const float*)d_in[9];
    const float* ln1_b  = (const float*)d_in[10];
    const float* ln2_g  = (const float*)d_in[11];
    const float* ln2_b  = (const float*)d_in[12];
    float* out = (float*)d_out;

    char* ws = (char*)d_ws;
    u16* wq = (u16*)(ws);               // qkv_w bf16
    u16* wp = (u16*)(ws + 6291456);     // proj_w bf16
    u16* w1 = (u16*)(ws + 8388608);     // fc1_w bf16
    u16* w2 = (u16*)(ws + 16777216);    // fc2_w bf16
    char* pool = ws + 25165824;
    u16* hbuf = (u16*)(pool);                   // ln1 out bf16 [8192,1024]   (0..16M)
    u16* qkb  = (u16*)(pool + 16777216);        // Q,K bf16 [8192,2048]       (16..48M)
    u16* vtb  = (u16*)(pool + 50331648);        // V^T bf16 [8,16,64,1024]    (48..64M)
    u16* ctxb = (u16*)(pool);                   // ctx bf16 (reuses hbuf)
    u16* h2b  = (u16*)(pool + 16777216);        // ln2 out (reuses qkb)
    u16* a1b  = (u16*)(pool + 33554432);        // gelu out bf16 [8192,4096]  (32..96M)

    cvt_kernel<<<3072, 256, 0, stream>>>(qkv_w, wq, 786432);
    cvt_kernel<<<1024, 256, 0, stream>>>(proj_w, wp, 262144);
    cvt_kernel<<<4096, 256, 0, stream>>>(fc1_w, w1, 1048576);
    cvt_kernel<<<4096, 256, 0, stream>>>(fc2_w, w2, 1048576);

    ln_kernel<<<8192, 256, 0, stream>>>(x, ln1_g, ln1_b, hbuf);
    // qkv: M=8192 N=3072 K=1024 -> 32x12 = 384 blocks (8-phase 256^2)
    gemm8_kernel<0,0,2><<<384, 512, 0, stream>>>(hbuf, wq, qkv_b, nullptr, qkb, vtb, 8192, 3072, 1024);
    attn_kernel<<<2048, 256, 0, stream>>>(qkb, vtb, ctxb);
    // proj: N=1024 -> 2-phase 128x256, 256 blocks
    gemm2_kernel<0,1,0><<<256, 512, 0, stream>>>(ctxb, wp, proj_b, x, out, nullptr, 8192, 1024, 1024);
    ln_kernel<<<8192, 256, 0, stream>>>(out, ln2_g, ln2_b, h2b);
    // fc1: M=8192 N=4096 K=1024 -> 32x16 = 512 blocks (8-phase 256^2)
    gemm8_kernel<1,0,1><<<512, 512, 0, stream>>>(h2b, w1, fc1_b, nullptr, a1b, nullptr, 8192, 4096, 1024);
    // fc2: N=1024 K=4096 -> 2-phase 128x256, 256 blocks
    gemm2_kernel<0,1,0><<<256, 512, 0, stream>>>(a1b, w2, fc2_b, out, out, nullptr, 8192, 1024, 4096);
}